// Round 9
// baseline (361.483 us; speedup 1.0000x reference)
//
#include <hip/hip_runtime.h>

#define N_NODES 50000
#define N_EDGES 800000
#define HID 128
#define AP2 132  // padded row stride (mult of 4 for b128; bank stride 4 => 2-way max, free)
#define NB 256   // node buckets
#define NPB 196  // nodes per bucket

__device__ __forceinline__ unsigned pack2bf(float a, float b) {
  unsigned ua = __float_as_uint(a);
  ua += 0x7FFFu + ((ua >> 16) & 1u);
  unsigned ub = __float_as_uint(b);
  ub += 0x7FFFu + ((ub >> 16) & 1u);
  return (ua >> 16) | (ub & 0xFFFF0000u);
}
#define BFLO(u) __uint_as_float((u) << 16)
#define BFHI(u) __uint_as_float((u) & 0xFFFF0000u)

// ================= bucketed CSR build =================

__global__ __launch_bounds__(256) void p1_hist_kernel(
    const int* __restrict__ src, const int* __restrict__ dst,
    int* __restrict__ bcnt_d, int* __restrict__ bcnt_s) {
  __shared__ int hd[NB], hs[NB];
  int t = threadIdx.x;
  hd[t] = 0; hs[t] = 0;
  __syncthreads();
  for (int e = blockIdx.x * 256 + t; e < N_EDGES; e += gridDim.x * 256) {
    atomicAdd(&hd[dst[e] / NPB], 1);
    atomicAdd(&hs[src[e] / NPB], 1);
  }
  __syncthreads();
  if (hd[t]) atomicAdd(&bcnt_d[t], hd[t]);
  if (hs[t]) atomicAdd(&bcnt_s[t], hs[t]);
}

__global__ void p2_scan_kernel(const int* __restrict__ bcnt_d, const int* __restrict__ bcnt_s,
                               int* __restrict__ bofs_d, int* __restrict__ bofs_s,
                               int* __restrict__ cur_d, int* __restrict__ cur_s) {
  __shared__ int s[NB];
  int t = threadIdx.x;
  int v = bcnt_d[t];
  s[t] = v;
  __syncthreads();
  for (int o = 1; o < NB; o <<= 1) {
    int x = (t >= o) ? s[t - o] : 0;
    __syncthreads();
    s[t] += x;
    __syncthreads();
  }
  int ofs = s[t] - v;
  bofs_d[t] = ofs; cur_d[t] = ofs;
  if (t == NB - 1) bofs_d[NB] = s[t];
  __syncthreads();
  v = bcnt_s[t];
  s[t] = v;
  __syncthreads();
  for (int o = 1; o < NB; o <<= 1) {
    int x = (t >= o) ? s[t - o] : 0;
    __syncthreads();
    s[t] += x;
    __syncthreads();
  }
  ofs = s[t] - v;
  bofs_s[t] = ofs; cur_s[t] = ofs;
  if (t == NB - 1) bofs_s[NB] = s[t];
}

__global__ __launch_bounds__(256) void p3_scatter_dst_kernel(
    const int* __restrict__ src, const int* __restrict__ dst,
    int* __restrict__ cur_d, int2* __restrict__ sdst) {
  __shared__ int bcnt[NB], bbase[NB];
  int t = threadIdx.x;
  int base = blockIdx.x * 2048;
  bcnt[t] = 0;
  __syncthreads();
  int myb[8], myr[8], mys[8], myp[8];
#pragma unroll
  for (int u = 0; u < 8; ++u) {
    int e = base + u * 256 + t;
    myb[u] = -1;
    if (e < N_EDGES) {
      int d = dst[e];
      int b = d / NPB;
      myb[u] = b;
      myr[u] = atomicAdd(&bcnt[b], 1);
      mys[u] = src[e];
      myp[u] = ((d - b * NPB) << 20) | e;
    }
  }
  __syncthreads();
  int c = bcnt[t];
  if (c) bbase[t] = atomicAdd(&cur_d[t], c);
  __syncthreads();
#pragma unroll
  for (int u = 0; u < 8; ++u) {
    if (myb[u] >= 0) sdst[bbase[myb[u]] + myr[u]] = make_int2(mys[u], myp[u]);
  }
}

__global__ __launch_bounds__(256) void p3_scatter_src_kernel(
    const int* __restrict__ src, int* __restrict__ cur_s, int* __restrict__ ssrc) {
  __shared__ int bcnt[NB], bbase[NB];
  int t = threadIdx.x;
  int base = blockIdx.x * 2048;
  bcnt[t] = 0;
  __syncthreads();
  int myb[8], myr[8], mys[8];
#pragma unroll
  for (int u = 0; u < 8; ++u) {
    int e = base + u * 256 + t;
    myb[u] = -1;
    if (e < N_EDGES) {
      int s = src[e];
      int b = s / NPB;
      myb[u] = b;
      myr[u] = atomicAdd(&bcnt[b], 1);
      mys[u] = s;
    }
  }
  __syncthreads();
  int c = bcnt[t];
  if (c) bbase[t] = atomicAdd(&cur_s[t], c);
  __syncthreads();
#pragma unroll
  for (int u = 0; u < 8; ++u) {
    if (myb[u] >= 0) ssrc[bbase[myb[u]] + myr[u]] = mys[u];
  }
}

__global__ __launch_bounds__(256) void p4_csr_kernel(
    const int2* __restrict__ sdst, const int* __restrict__ bofs_d,
    int* __restrict__ row_ofs, float* __restrict__ norm_in,
    int* __restrict__ csr_src, int* __restrict__ csr_eid) {
  __shared__ int hc[NB], sc[NB], cur[NB];
  int b = blockIdx.x, t = threadIdx.x;
  int base = bofs_d[b], cnt = bofs_d[b + 1] - base;
  hc[t] = 0;
  __syncthreads();
  for (int i = t; i < cnt; i += 256) atomicAdd(&hc[sdst[base + i].y >> 20], 1);
  __syncthreads();
  int v = hc[t];
  sc[t] = v;
  __syncthreads();
  for (int o = 1; o < NB; o <<= 1) {
    int x = (t >= o) ? sc[t - o] : 0;
    __syncthreads();
    sc[t] += x;
    __syncthreads();
  }
  int ofs = sc[t] - v;
  int node = b * NPB + t;
  if (t < NPB && node < N_NODES) {
    row_ofs[node] = base + ofs;
    norm_in[node] = rsqrtf((float)(v < 1 ? 1 : v));
  }
  cur[t] = base + ofs;
  if (b == 0 && t == 0) row_ofs[N_NODES] = N_EDGES;
  __syncthreads();
  for (int i = t; i < cnt; i += 256) {
    int2 e = sdst[base + i];
    int pos = atomicAdd(&cur[e.y >> 20], 1);
    csr_src[pos] = e.x;
    csr_eid[pos] = e.y & 0xFFFFF;
  }
}

__global__ __launch_bounds__(256) void p5_degout_kernel(
    const int* __restrict__ ssrc, const int* __restrict__ bofs_s,
    float* __restrict__ norm_out) {
  __shared__ int hc[NB];
  int b = blockIdx.x, t = threadIdx.x;
  int base = bofs_s[b], cnt = bofs_s[b + 1] - base;
  int lo = b * NPB;
  hc[t] = 0;
  __syncthreads();
  for (int i = t; i < cnt; i += 256) atomicAdd(&hc[ssrc[base + i] - lo], 1);
  __syncthreads();
  int node = lo + t;
  if (t < NPB && node < N_NODES) {
    int v = hc[t];
    norm_out[node] = rsqrtf((float)(v < 1 ? 1 : v));
  }
}

// ================= model kernels =================

__global__ __launch_bounds__(256) void agg4_kernel(
    const float4* __restrict__ nf4, const float* __restrict__ no_,
    const int* __restrict__ csr_src, const int* __restrict__ row_ofs,
    float4* __restrict__ agg4, float* __restrict__ sno) {
  int wid = (blockIdx.x * blockDim.x + threadIdx.x) >> 6;
  int lane = threadIdx.x & 63;
  int g = lane >> 4, l = lane & 15;
  int v = wid * 4 + g;
  if (v >= N_NODES) return;
  int beg = row_ofs[v], end = row_ofs[v + 1];
  float ax = 0.f, ay = 0.f, az = 0.f, aw = 0.f, sn = 0.f;
  for (int i = beg + l; i < end; i += 16) {
    int s = csr_src[i];
    float w = no_[s];
    float4 n = nf4[s];
    ax += n.x * w; ay += n.y * w; az += n.z * w; aw += n.w * w;
    sn += w;
  }
#pragma unroll
  for (int o = 1; o < 16; o <<= 1) {
    ax += __shfl_xor(ax, o, 16);
    ay += __shfl_xor(ay, o, 16);
    az += __shfl_xor(az, o, 16);
    aw += __shfl_xor(aw, o, 16);
    sn += __shfl_xor(sn, o, 16);
  }
  if (l == 0) {
    agg4[v] = make_float4(ax, ay, az, aw);
    sno[v] = sn;
  }
}

// layer-1: fused 4->128 expand + GEMM; W0 read directly from global (L1/L2 broadcast)
__global__ __launch_bounds__(256) void gemm_l1_kernel(
    const float4* __restrict__ agg4, const float* __restrict__ sno,
    const float* __restrict__ ni_, const float* __restrict__ no_,
    const float* __restrict__ Wn, const float* __restrict__ bn,
    const float* __restrict__ W0, const float* __restrict__ b0,
    uint4* __restrict__ h1b, int nrows) {
  __shared__ float At[HID * 64];      // 32 KB, k-major
  int t = threadIdx.x;
  int v0 = blockIdx.x * 64;
  {
    int r = t & 63, kg = t >> 6;
    int v = v0 + r;
    float4 a = make_float4(0.f, 0.f, 0.f, 0.f);
    float sn = 0.f, nin = 0.f;
    if (v < nrows) { a = agg4[v]; sn = sno[v]; nin = ni_[v]; }
    for (int kk = 0; kk < 32; ++kk) {
      int k = kg * 32 + kk;  // wave-uniform
      float val = (a.x * Wn[k] + a.y * Wn[HID + k] + a.z * Wn[2 * HID + k] +
                   a.w * Wn[3 * HID + k] + bn[k] * sn) * nin;
      At[k * 64 + r] = val;
    }
  }
  __syncthreads();
  int c0 = (t >> 4) * 8, r0 = (t & 15) * 4;
  float acc[4][8];
#pragma unroll
  for (int i = 0; i < 4; ++i)
#pragma unroll
    for (int j = 0; j < 8; ++j) acc[i][j] = 0.f;

#pragma unroll 4
  for (int k = 0; k < HID; ++k) {
    float4 av = *(const float4*)&At[k * 64 + r0];
    float4 w0v = *(const float4*)&W0[k * HID + c0];
    float4 w1v = *(const float4*)&W0[k * HID + c0 + 4];
    float ar[4] = {av.x, av.y, av.z, av.w};
    float wv[8] = {w0v.x, w0v.y, w0v.z, w0v.w, w1v.x, w1v.y, w1v.z, w1v.w};
#pragma unroll
    for (int i = 0; i < 4; ++i)
#pragma unroll
      for (int j = 0; j < 8; ++j) acc[i][j] += ar[i] * wv[j];
  }
  float bb[8];
  {
    float4 b0v = *(const float4*)&b0[c0];
    float4 b1v = *(const float4*)&b0[c0 + 4];
    bb[0] = b0v.x; bb[1] = b0v.y; bb[2] = b0v.z; bb[3] = b0v.w;
    bb[4] = b1v.x; bb[5] = b1v.y; bb[6] = b1v.z; bb[7] = b1v.w;
  }
#pragma unroll
  for (int i = 0; i < 4; ++i) {
    int v = v0 + r0 + i;
    if (v < nrows) {
      float nov = no_[v];
      float o[8];
#pragma unroll
      for (int j = 0; j < 8; ++j) o[j] = fmaxf(acc[i][j] + bb[j], 0.f) * nov;
      uint4 pk;
      pk.x = pack2bf(o[0], o[1]); pk.y = pack2bf(o[2], o[3]);
      pk.z = pack2bf(o[4], o[5]); pk.w = pack2bf(o[6], o[7]);
      h1b[(size_t)v * 16 + (c0 >> 3)] = pk;
    }
  }
}

// layer-2 aggregate: bf16 row gathers (256B/row), f32 accumulate
__global__ __launch_bounds__(256) void aggregate_kernel(
    const uint4* __restrict__ hb, const int* __restrict__ row_ofs,
    const int* __restrict__ csr_src, const float* __restrict__ ni_,
    float* __restrict__ agg) {
  int v = (blockIdx.x * blockDim.x + threadIdx.x) >> 6;
  int lane = threadIdx.x & 63;
  if (v >= N_NODES) return;
  int beg = row_ofs[v], end = row_ofs[v + 1];
  int g = lane >> 4, l = lane & 15;
  float acc[8];
#pragma unroll
  for (int j = 0; j < 8; ++j) acc[j] = 0.f;
  for (int i = beg; i < end; i += 16) {
    int ii[4]; float mm[4]; int ss[4];
#pragma unroll
    for (int u = 0; u < 4; ++u) {
      ii[u] = i + 4 * u + g;
      bool q = ii[u] < end;
      mm[u] = q ? 1.f : 0.f;
      ss[u] = csr_src[q ? ii[u] : beg];
    }
    uint4 X[4];
#pragma unroll
    for (int u = 0; u < 4; ++u) X[u] = hb[(size_t)ss[u] * 16 + l];
#pragma unroll
    for (int u = 0; u < 4; ++u) {
      acc[0] += BFLO(X[u].x) * mm[u]; acc[1] += BFHI(X[u].x) * mm[u];
      acc[2] += BFLO(X[u].y) * mm[u]; acc[3] += BFHI(X[u].y) * mm[u];
      acc[4] += BFLO(X[u].z) * mm[u]; acc[5] += BFHI(X[u].z) * mm[u];
      acc[6] += BFLO(X[u].w) * mm[u]; acc[7] += BFHI(X[u].w) * mm[u];
    }
  }
#pragma unroll
  for (int j = 0; j < 8; ++j) {
    acc[j] += __shfl_xor(acc[j], 16, 64);
    acc[j] += __shfl_xor(acc[j], 32, 64);
  }
  if (g == 0) {
    float n = ni_[v];
    float4 o0 = make_float4(acc[0] * n, acc[1] * n, acc[2] * n, acc[3] * n);
    float4 o1 = make_float4(acc[4] * n, acc[5] * n, acc[6] * n, acc[7] * n);
    *(float4*)&agg[(size_t)v * HID + l * 8] = o0;
    *(float4*)&agg[(size_t)v * HID + l * 8 + 4] = o1;
  }
}

// fused layer-2 GEMM + output GEMM; W from global (L1/L2), As-only LDS, 3 barriers
__global__ __launch_bounds__(256) void gemm_dual_kernel(
    const float* __restrict__ in, const float* __restrict__ W0,
    const float* __restrict__ b0, const float* __restrict__ W1,
    uint4* __restrict__ yb, int nrows) {
  __shared__ float As[64 * AP2];      // 33 KB
  int t = threadIdx.x;
  int v0 = blockIdx.x * 64;
  {
    const float4* in4 = (const float4*)in;
#pragma unroll
    for (int i = 0; i < 8; ++i) {
      int idx = i * 256 + t;
      int r = idx >> 5, q = idx & 31;
      int v = v0 + r;
      float4 val = make_float4(0.f, 0.f, 0.f, 0.f);
      if (v < nrows) val = in4[(size_t)v * 32 + q];
      *(float4*)&As[r * AP2 + q * 4] = val;
    }
  }
  __syncthreads();
  int c0 = (t >> 4) * 8, m = t & 15;
  float acc[4][8];
#pragma unroll
  for (int i = 0; i < 4; ++i)
#pragma unroll
    for (int j = 0; j < 8; ++j) acc[i][j] = 0.f;

  // ---- GEMM 1: acc = A @ W0 ----
#pragma unroll 4
  for (int k = 0; k < HID; ++k) {
    float4 w0v = *(const float4*)&W0[k * HID + c0];
    float4 w1v = *(const float4*)&W0[k * HID + c0 + 4];
    float ar[4];
#pragma unroll
    for (int i = 0; i < 4; ++i) ar[i] = As[(m + 16 * i) * AP2 + k];
    float wv[8] = {w0v.x, w0v.y, w0v.z, w0v.w, w1v.x, w1v.y, w1v.z, w1v.w};
#pragma unroll
    for (int i = 0; i < 4; ++i)
#pragma unroll
      for (int j = 0; j < 8; ++j) acc[i][j] += ar[i] * wv[j];
  }
  __syncthreads();
  {
    float bb[8];
    float4 b0v = *(const float4*)&b0[c0];
    float4 b1v = *(const float4*)&b0[c0 + 4];
    bb[0] = b0v.x; bb[1] = b0v.y; bb[2] = b0v.z; bb[3] = b0v.w;
    bb[4] = b1v.x; bb[5] = b1v.y; bb[6] = b1v.z; bb[7] = b1v.w;
#pragma unroll
    for (int i = 0; i < 4; ++i) {
      float4 o0, o1;
      o0.x = fmaxf(acc[i][0] + bb[0], 0.f); o0.y = fmaxf(acc[i][1] + bb[1], 0.f);
      o0.z = fmaxf(acc[i][2] + bb[2], 0.f); o0.w = fmaxf(acc[i][3] + bb[3], 0.f);
      o1.x = fmaxf(acc[i][4] + bb[4], 0.f); o1.y = fmaxf(acc[i][5] + bb[5], 0.f);
      o1.z = fmaxf(acc[i][6] + bb[6], 0.f); o1.w = fmaxf(acc[i][7] + bb[7], 0.f);
      *(float4*)&As[(m + 16 * i) * AP2 + c0] = o0;
      *(float4*)&As[(m + 16 * i) * AP2 + c0 + 4] = o1;
#pragma unroll
      for (int j = 0; j < 8; ++j) acc[i][j] = 0.f;
    }
  }
  __syncthreads();
  // ---- GEMM 2: acc = T1 @ W1 ----
#pragma unroll 4
  for (int k = 0; k < HID; ++k) {
    float4 w0v = *(const float4*)&W1[k * HID + c0];
    float4 w1v = *(const float4*)&W1[k * HID + c0 + 4];
    float ar[4];
#pragma unroll
    for (int i = 0; i < 4; ++i) ar[i] = As[(m + 16 * i) * AP2 + k];
    float wv[8] = {w0v.x, w0v.y, w0v.z, w0v.w, w1v.x, w1v.y, w1v.z, w1v.w};
#pragma unroll
    for (int i = 0; i < 4; ++i)
#pragma unroll
      for (int j = 0; j < 8; ++j) acc[i][j] += ar[i] * wv[j];
  }
#pragma unroll
  for (int i = 0; i < 4; ++i) {
    int v = v0 + m + 16 * i;
    if (v < nrows) {
      uint4 pk;
      pk.x = pack2bf(acc[i][0], acc[i][1]); pk.y = pack2bf(acc[i][2], acc[i][3]);
      pk.z = pack2bf(acc[i][4], acc[i][5]); pk.w = pack2bf(acc[i][6], acc[i][7]);
      yb[(size_t)v * 16 + (c0 >> 3)] = pk;
    }
  }
}

// edge output: bf16 y gathers (256B/row), f32 math
__global__ __launch_bounds__(256) void edge_out_kernel(
    const int* __restrict__ csr_src, const int* __restrict__ csr_eid,
    const int* __restrict__ row_ofs, const uint4* __restrict__ yb,
    const float* __restrict__ b1, const float* __restrict__ w2,
    const float* __restrict__ b2, float* __restrict__ out) {
  int v = (blockIdx.x * blockDim.x + threadIdx.x) >> 6;
  int lane = threadIdx.x & 63;
  if (v >= N_NODES) return;
  int beg = row_ofs[v], end = row_ofs[v + 1];
  if (beg >= end) return;
  int g = lane >> 4, l = lane & 15;
  uint4 D = yb[(size_t)v * 16 + l];
  float d[8] = {BFLO(D.x), BFHI(D.x), BFLO(D.y), BFHI(D.y),
                BFLO(D.z), BFHI(D.z), BFLO(D.w), BFHI(D.w)};
  {
    float4 q0 = ((const float4*)b1)[l * 2], q1 = ((const float4*)b1)[l * 2 + 1];
    d[0] += q0.x; d[1] += q0.y; d[2] += q0.z; d[3] += q0.w;
    d[4] += q1.x; d[5] += q1.y; d[6] += q1.z; d[7] += q1.w;
  }
  float w[8];
  {
    float4 q0 = ((const float4*)w2)[l * 2], q1 = ((const float4*)w2)[l * 2 + 1];
    w[0] = q0.x; w[1] = q0.y; w[2] = q0.z; w[3] = q0.w;
    w[4] = q1.x; w[5] = q1.y; w[6] = q1.z; w[7] = q1.w;
  }
  float ob2 = b2[0];
  for (int i = beg; i < end; i += 16) {
    int ii[4]; bool qq[4]; int ss[4];
#pragma unroll
    for (int u = 0; u < 4; ++u) {
      ii[u] = i + 4 * u + g;
      qq[u] = ii[u] < end;
      ss[u] = csr_src[qq[u] ? ii[u] : beg];
    }
    uint4 A[4];
#pragma unroll
    for (int u = 0; u < 4; ++u) A[u] = yb[(size_t)ss[u] * 16 + l];
#pragma unroll
    for (int u = 0; u < 4; ++u) {
      float p = fmaxf(BFLO(A[u].x) + d[0], 0.f) * w[0] +
                fmaxf(BFHI(A[u].x) + d[1], 0.f) * w[1] +
                fmaxf(BFLO(A[u].y) + d[2], 0.f) * w[2] +
                fmaxf(BFHI(A[u].y) + d[3], 0.f) * w[3] +
                fmaxf(BFLO(A[u].z) + d[4], 0.f) * w[4] +
                fmaxf(BFHI(A[u].z) + d[5], 0.f) * w[5] +
                fmaxf(BFLO(A[u].w) + d[6], 0.f) * w[6] +
                fmaxf(BFHI(A[u].w) + d[7], 0.f) * w[7];
      p += __shfl_down(p, 8, 16);
      p += __shfl_down(p, 4, 16);
      p += __shfl_down(p, 2, 16);
      p += __shfl_down(p, 1, 16);
      if (l == 0 && qq[u]) out[csr_eid[ii[u]]] = p + ob2;
    }
  }
}

extern "C" void kernel_launch(void* const* d_in, const int* in_sizes, int n_in,
                              void* d_out, int out_size, void* d_ws, size_t ws_size,
                              hipStream_t stream) {
  const float* node_feats = (const float*)d_in[1];
  const int*   src        = (const int*)d_in[2];
  const int*   dst        = (const int*)d_in[3];
  const float* W_nemb     = (const float*)d_in[6];
  const float* b_nemb     = (const float*)d_in[7];
  const float* gnn_W      = (const float*)d_in[8];
  const float* gnn_b      = (const float*)d_in[9];
  const float* out_W1     = (const float*)d_in[10];
  const float* out_b1     = (const float*)d_in[11];
  const float* out_W2     = (const float*)d_in[12];
  const float* out_b2     = (const float*)d_in[13];
  float* out = (float*)d_out;

  size_t off = 0;
  char* base = (char*)d_ws;
  auto alloc = [&](size_t nbytes) -> char* {
    off = (off + 255) & ~(size_t)255;
    char* p = base + off;
    off += nbytes;
    return p;
  };
  int*    bcnt2    = (int*)alloc(2 * NB * 4);
  int*    bofs_d   = (int*)alloc((NB + 1) * 4);
  int*    bofs_s   = (int*)alloc((NB + 1) * 4);
  int*    cur_d    = (int*)alloc(NB * 4);
  int*    cur_s    = (int*)alloc(NB * 4);
  float*  norm_out = (float*)alloc(N_NODES * 4);
  float*  norm_in  = (float*)alloc(N_NODES * 4);
  int*    row_ofs  = (int*)alloc((N_NODES + 1) * 4);
  int*    csr_src  = (int*)alloc((size_t)N_EDGES * 4);
  int*    csr_eid  = (int*)alloc((size_t)N_EDGES * 4);
  float4* agg4     = (float4*)alloc((size_t)N_NODES * 16);
  float*  sno      = (float*)alloc(N_NODES * 4);
  uint4*  h1b      = (uint4*)alloc((size_t)N_NODES * HID * 2);   // bf16 h1*no
  float*  aggbuf   = (float*)alloc((size_t)N_NODES * HID * 4);   // f32 agg
  uint4*  yb       = (uint4*)alloc((size_t)N_NODES * HID * 2);   // bf16 y
  int2*   sdst     = (int2*)aggbuf;  // staging alias, consumed by p4
  int*    ssrc     = (int*)yb;       // staging alias, consumed by p5
  int*    bcnt_d   = bcnt2;
  int*    bcnt_s   = bcnt2 + NB;
  (void)ws_size; (void)n_in; (void)in_sizes; (void)out_size;

  hipMemsetAsync(bcnt2, 0, 2 * NB * 4, stream);
  p1_hist_kernel<<<128, 256, 0, stream>>>(src, dst, bcnt_d, bcnt_s);
  p2_scan_kernel<<<1, 256, 0, stream>>>(bcnt_d, bcnt_s, bofs_d, bofs_s, cur_d, cur_s);
  p3_scatter_dst_kernel<<<(N_EDGES + 2047) / 2048, 256, 0, stream>>>(src, dst, cur_d, sdst);
  p3_scatter_src_kernel<<<(N_EDGES + 2047) / 2048, 256, 0, stream>>>(src, cur_s, ssrc);
  p4_csr_kernel<<<NB, 256, 0, stream>>>(sdst, bofs_d, row_ofs, norm_in, csr_src, csr_eid);
  p5_degout_kernel<<<NB, 256, 0, stream>>>(ssrc, bofs_s, norm_out);

  agg4_kernel<<<(N_NODES * 16 + 255) / 256, 256, 0, stream>>>(
      (const float4*)node_feats, norm_out, csr_src, row_ofs, agg4, sno);
  gemm_l1_kernel<<<(N_NODES + 63) / 64, 256, 0, stream>>>(
      agg4, sno, norm_in, norm_out, W_nemb, b_nemb, gnn_W, gnn_b, h1b, N_NODES);

  aggregate_kernel<<<(N_NODES * 64 + 255) / 256, 256, 0, stream>>>(
      h1b, row_ofs, csr_src, norm_in, aggbuf);

  gemm_dual_kernel<<<(N_NODES + 63) / 64, 256, 0, stream>>>(
      aggbuf, gnn_W + (size_t)HID * HID, gnn_b + HID, out_W1, yb, N_NODES);

  edge_out_kernel<<<(N_NODES * 64 + 255) / 256, 256, 0, stream>>>(
      csr_src, csr_eid, row_ofs, yb, out_b1, out_W2, out_b2, out);
}

// Round 10
// 320.326 us; speedup vs baseline: 1.1285x; 1.1285x over previous
//
#include <hip/hip_runtime.h>

#define N_NODES 50000
#define N_EDGES 800000
#define HID 128
#define NB 256   // node buckets
#define NPB 196  // nodes per bucket
#define TP 136   // T1 LDS row stride in shorts (272B: 16B-aligned, bank-spread)

typedef __attribute__((ext_vector_type(8))) short bf16x8;
typedef __attribute__((ext_vector_type(4))) float f32x4;

__device__ __forceinline__ unsigned pack2bf(float a, float b) {
  unsigned ua = __float_as_uint(a);
  ua += 0x7FFFu + ((ua >> 16) & 1u);
  unsigned ub = __float_as_uint(b);
  ub += 0x7FFFu + ((ub >> 16) & 1u);
  return (ua >> 16) | (ub & 0xFFFF0000u);
}
#define BFLO(u) __uint_as_float((u) << 16)
#define BFHI(u) __uint_as_float((u) & 0xFFFF0000u)

// ================= bucketed CSR build =================

__global__ __launch_bounds__(256) void p1_hist_kernel(
    const int* __restrict__ src, const int* __restrict__ dst,
    int* __restrict__ bcnt_d, int* __restrict__ bcnt_s) {
  __shared__ int hd[NB], hs[NB];
  int t = threadIdx.x;
  hd[t] = 0; hs[t] = 0;
  __syncthreads();
  for (int e = blockIdx.x * 256 + t; e < N_EDGES; e += gridDim.x * 256) {
    atomicAdd(&hd[dst[e] / NPB], 1);
    atomicAdd(&hs[src[e] / NPB], 1);
  }
  __syncthreads();
  if (hd[t]) atomicAdd(&bcnt_d[t], hd[t]);
  if (hs[t]) atomicAdd(&bcnt_s[t], hs[t]);
}

__global__ void p2_scan_kernel(const int* __restrict__ bcnt_d, const int* __restrict__ bcnt_s,
                               int* __restrict__ bofs_d, int* __restrict__ bofs_s,
                               int* __restrict__ cur_d, int* __restrict__ cur_s) {
  __shared__ int s[NB];
  int t = threadIdx.x;
  int v = bcnt_d[t];
  s[t] = v;
  __syncthreads();
  for (int o = 1; o < NB; o <<= 1) {
    int x = (t >= o) ? s[t - o] : 0;
    __syncthreads();
    s[t] += x;
    __syncthreads();
  }
  int ofs = s[t] - v;
  bofs_d[t] = ofs; cur_d[t] = ofs;
  if (t == NB - 1) bofs_d[NB] = s[t];
  __syncthreads();
  v = bcnt_s[t];
  s[t] = v;
  __syncthreads();
  for (int o = 1; o < NB; o <<= 1) {
    int x = (t >= o) ? s[t - o] : 0;
    __syncthreads();
    s[t] += x;
    __syncthreads();
  }
  ofs = s[t] - v;
  bofs_s[t] = ofs; cur_s[t] = ofs;
  if (t == NB - 1) bofs_s[NB] = s[t];
}

__global__ __launch_bounds__(256) void p3_scatter_dst_kernel(
    const int* __restrict__ src, const int* __restrict__ dst,
    int* __restrict__ cur_d, int2* __restrict__ sdst) {
  __shared__ int bcnt[NB], bbase[NB];
  int t = threadIdx.x;
  int base = blockIdx.x * 2048;
  bcnt[t] = 0;
  __syncthreads();
  int myb[8], myr[8], mys[8], myp[8];
#pragma unroll
  for (int u = 0; u < 8; ++u) {
    int e = base + u * 256 + t;
    myb[u] = -1;
    if (e < N_EDGES) {
      int d = dst[e];
      int b = d / NPB;
      myb[u] = b;
      myr[u] = atomicAdd(&bcnt[b], 1);
      mys[u] = src[e];
      myp[u] = ((d - b * NPB) << 20) | e;
    }
  }
  __syncthreads();
  int c = bcnt[t];
  if (c) bbase[t] = atomicAdd(&cur_d[t], c);
  __syncthreads();
#pragma unroll
  for (int u = 0; u < 8; ++u) {
    if (myb[u] >= 0) sdst[bbase[myb[u]] + myr[u]] = make_int2(mys[u], myp[u]);
  }
}

__global__ __launch_bounds__(256) void p3_scatter_src_kernel(
    const int* __restrict__ src, int* __restrict__ cur_s, int* __restrict__ ssrc) {
  __shared__ int bcnt[NB], bbase[NB];
  int t = threadIdx.x;
  int base = blockIdx.x * 2048;
  bcnt[t] = 0;
  __syncthreads();
  int myb[8], myr[8], mys[8];
#pragma unroll
  for (int u = 0; u < 8; ++u) {
    int e = base + u * 256 + t;
    myb[u] = -1;
    if (e < N_EDGES) {
      int s = src[e];
      int b = s / NPB;
      myb[u] = b;
      myr[u] = atomicAdd(&bcnt[b], 1);
      mys[u] = s;
    }
  }
  __syncthreads();
  int c = bcnt[t];
  if (c) bbase[t] = atomicAdd(&cur_s[t], c);
  __syncthreads();
#pragma unroll
  for (int u = 0; u < 8; ++u) {
    if (myb[u] >= 0) ssrc[bbase[myb[u]] + myr[u]] = mys[u];
  }
}

__global__ __launch_bounds__(256) void p4_csr_kernel(
    const int2* __restrict__ sdst, const int* __restrict__ bofs_d,
    int* __restrict__ row_ofs, float* __restrict__ norm_in,
    int* __restrict__ csr_src, int* __restrict__ csr_eid) {
  __shared__ int hc[NB], sc[NB], cur[NB];
  int b = blockIdx.x, t = threadIdx.x;
  int base = bofs_d[b], cnt = bofs_d[b + 1] - base;
  hc[t] = 0;
  __syncthreads();
  for (int i = t; i < cnt; i += 256) atomicAdd(&hc[sdst[base + i].y >> 20], 1);
  __syncthreads();
  int v = hc[t];
  sc[t] = v;
  __syncthreads();
  for (int o = 1; o < NB; o <<= 1) {
    int x = (t >= o) ? sc[t - o] : 0;
    __syncthreads();
    sc[t] += x;
    __syncthreads();
  }
  int ofs = sc[t] - v;
  int node = b * NPB + t;
  if (t < NPB && node < N_NODES) {
    row_ofs[node] = base + ofs;
    norm_in[node] = rsqrtf((float)(v < 1 ? 1 : v));
  }
  cur[t] = base + ofs;
  if (b == 0 && t == 0) row_ofs[N_NODES] = N_EDGES;
  __syncthreads();
  for (int i = t; i < cnt; i += 256) {
    int2 e = sdst[base + i];
    int pos = atomicAdd(&cur[e.y >> 20], 1);
    csr_src[pos] = e.x;
    csr_eid[pos] = e.y & 0xFFFFF;
  }
}

__global__ __launch_bounds__(256) void p5_degout_kernel(
    const int* __restrict__ ssrc, const int* __restrict__ bofs_s,
    float* __restrict__ norm_out) {
  __shared__ int hc[NB];
  int b = blockIdx.x, t = threadIdx.x;
  int base = bofs_s[b], cnt = bofs_s[b + 1] - base;
  int lo = b * NPB;
  hc[t] = 0;
  __syncthreads();
  for (int i = t; i < cnt; i += 256) atomicAdd(&hc[ssrc[base + i] - lo], 1);
  __syncthreads();
  int node = lo + t;
  if (t < NPB && node < N_NODES) {
    int v = hc[t];
    norm_out[node] = rsqrtf((float)(v < 1 ? 1 : v));
  }
}

// W prep: Wt[n][k] = bf16(W[k][n]) for layer-2 W and out_W1
__global__ __launch_bounds__(256) void prep_w_kernel(
    const float* __restrict__ W0, const float* __restrict__ W1,
    short* __restrict__ Wt0, short* __restrict__ Wt1) {
  int t = blockIdx.x * 256 + threadIdx.x;
  if (t < HID * HID) {
    int k = t >> 7, n = t & 127;
    Wt0[n * HID + k] = (short)(pack2bf(W0[t], 0.f) & 0xFFFFu);
    Wt1[n * HID + k] = (short)(pack2bf(W1[t], 0.f) & 0xFFFFu);
  }
}

// ================= model kernels =================

__global__ __launch_bounds__(256) void agg4_kernel(
    const float4* __restrict__ nf4, const float* __restrict__ no_,
    const int* __restrict__ csr_src, const int* __restrict__ row_ofs,
    float4* __restrict__ agg4, float* __restrict__ sno) {
  int wid = (blockIdx.x * blockDim.x + threadIdx.x) >> 6;
  int lane = threadIdx.x & 63;
  int g = lane >> 4, l = lane & 15;
  int v = wid * 4 + g;
  if (v >= N_NODES) return;
  int beg = row_ofs[v], end = row_ofs[v + 1];
  float ax = 0.f, ay = 0.f, az = 0.f, aw = 0.f, sn = 0.f;
  for (int i = beg + l; i < end; i += 16) {
    int s = csr_src[i];
    float w = no_[s];
    float4 n = nf4[s];
    ax += n.x * w; ay += n.y * w; az += n.z * w; aw += n.w * w;
    sn += w;
  }
#pragma unroll
  for (int o = 1; o < 16; o <<= 1) {
    ax += __shfl_xor(ax, o, 16);
    ay += __shfl_xor(ay, o, 16);
    az += __shfl_xor(az, o, 16);
    aw += __shfl_xor(aw, o, 16);
    sn += __shfl_xor(sn, o, 16);
  }
  if (l == 0) {
    agg4[v] = make_float4(ax, ay, az, aw);
    sno[v] = sn;
  }
}

// layer-1: fused 4->128 expand + GEMM (R8-proven Wbuf version); bf16 output
__global__ __launch_bounds__(256) void gemm_l1_kernel(
    const float4* __restrict__ agg4, const float* __restrict__ sno,
    const float* __restrict__ ni_, const float* __restrict__ no_,
    const float* __restrict__ Wn, const float* __restrict__ bn,
    const float* __restrict__ W0, const float* __restrict__ b0,
    uint4* __restrict__ h1b, int nrows) {
  __shared__ float At[HID * 64];      // 32 KB, k-major
  __shared__ float Wbuf[32 * HID];    // 16 KB
  int t = threadIdx.x;
  int v0 = blockIdx.x * 64;
  {
    int r = t & 63, kg = t >> 6;
    int v = v0 + r;
    float4 a = make_float4(0.f, 0.f, 0.f, 0.f);
    float sn = 0.f, nin = 0.f;
    if (v < nrows) { a = agg4[v]; sn = sno[v]; nin = ni_[v]; }
    for (int kk = 0; kk < 32; ++kk) {
      int k = kg * 32 + kk;  // wave-uniform
      float val = (a.x * Wn[k] + a.y * Wn[HID + k] + a.z * Wn[2 * HID + k] +
                   a.w * Wn[3 * HID + k] + bn[k] * sn) * nin;
      At[k * 64 + r] = val;
    }
  }
  int c0 = (t >> 4) * 8, r0 = (t & 15) * 4;
  float acc[4][8];
#pragma unroll
  for (int i = 0; i < 4; ++i)
#pragma unroll
    for (int j = 0; j < 8; ++j) acc[i][j] = 0.f;

  for (int kc = 0; kc < HID; kc += 32) {
    __syncthreads();
    {
      const float4* wsrc = (const float4*)(W0 + kc * HID);
      float4* wdst = (float4*)Wbuf;
#pragma unroll
      for (int i = 0; i < 4; ++i) wdst[i * 256 + t] = wsrc[i * 256 + t];
    }
    __syncthreads();
#pragma unroll 4
    for (int kk = 0; kk < 32; ++kk) {
      float4 av = *(const float4*)&At[(kc + kk) * 64 + r0];
      float4 w0v = *(const float4*)&Wbuf[kk * HID + c0];
      float4 w1v = *(const float4*)&Wbuf[kk * HID + c0 + 4];
      float ar[4] = {av.x, av.y, av.z, av.w};
      float wv[8] = {w0v.x, w0v.y, w0v.z, w0v.w, w1v.x, w1v.y, w1v.z, w1v.w};
#pragma unroll
      for (int i = 0; i < 4; ++i)
#pragma unroll
        for (int j = 0; j < 8; ++j) acc[i][j] += ar[i] * wv[j];
    }
  }
  float bb[8];
  {
    float4 b0v = *(const float4*)&b0[c0];
    float4 b1v = *(const float4*)&b0[c0 + 4];
    bb[0] = b0v.x; bb[1] = b0v.y; bb[2] = b0v.z; bb[3] = b0v.w;
    bb[4] = b1v.x; bb[5] = b1v.y; bb[6] = b1v.z; bb[7] = b1v.w;
  }
#pragma unroll
  for (int i = 0; i < 4; ++i) {
    int v = v0 + r0 + i;
    if (v < nrows) {
      float nov = no_[v];
      float o[8];
#pragma unroll
      for (int j = 0; j < 8; ++j) o[j] = fmaxf(acc[i][j] + bb[j], 0.f) * nov;
      uint4 pk;
      pk.x = pack2bf(o[0], o[1]); pk.y = pack2bf(o[2], o[3]);
      pk.z = pack2bf(o[4], o[5]); pk.w = pack2bf(o[6], o[7]);
      h1b[(size_t)v * 16 + (c0 >> 3)] = pk;
    }
  }
}

// layer-2 aggregate: bf16 row gathers, f32 accumulate, bf16 OUTPUT (A for MFMA)
__global__ __launch_bounds__(256) void aggregate_kernel(
    const uint4* __restrict__ hb, const int* __restrict__ row_ofs,
    const int* __restrict__ csr_src, const float* __restrict__ ni_,
    uint4* __restrict__ Ab) {
  int v = (blockIdx.x * blockDim.x + threadIdx.x) >> 6;
  int lane = threadIdx.x & 63;
  if (v >= N_NODES) return;
  int beg = row_ofs[v], end = row_ofs[v + 1];
  int g = lane >> 4, l = lane & 15;
  float acc[8];
#pragma unroll
  for (int j = 0; j < 8; ++j) acc[j] = 0.f;
  for (int i = beg; i < end; i += 16) {
    int ii[4]; float mm[4]; int ss[4];
#pragma unroll
    for (int u = 0; u < 4; ++u) {
      ii[u] = i + 4 * u + g;
      bool q = ii[u] < end;
      mm[u] = q ? 1.f : 0.f;
      ss[u] = csr_src[q ? ii[u] : beg];
    }
    uint4 X[4];
#pragma unroll
    for (int u = 0; u < 4; ++u) X[u] = hb[(size_t)ss[u] * 16 + l];
#pragma unroll
    for (int u = 0; u < 4; ++u) {
      acc[0] += BFLO(X[u].x) * mm[u]; acc[1] += BFHI(X[u].x) * mm[u];
      acc[2] += BFLO(X[u].y) * mm[u]; acc[3] += BFHI(X[u].y) * mm[u];
      acc[4] += BFLO(X[u].z) * mm[u]; acc[5] += BFHI(X[u].z) * mm[u];
      acc[6] += BFLO(X[u].w) * mm[u]; acc[7] += BFHI(X[u].w) * mm[u];
    }
  }
#pragma unroll
  for (int j = 0; j < 8; ++j) {
    acc[j] += __shfl_xor(acc[j], 16, 64);
    acc[j] += __shfl_xor(acc[j], 32, 64);
  }
  if (g == 0) {
    float n = ni_[v];
    uint4 pk;
    pk.x = pack2bf(acc[0] * n, acc[1] * n);
    pk.y = pack2bf(acc[2] * n, acc[3] * n);
    pk.z = pack2bf(acc[4] * n, acc[5] * n);
    pk.w = pack2bf(acc[6] * n, acc[7] * n);
    Ab[(size_t)v * 16 + l] = pk;
  }
}

// fused layer-2 GEMM + output GEMM via MFMA 16x16x32 bf16.
// Computes transposed products D = W^T (A-op) x X^T (B-op):
//   C/D: col=lane&15 = node row, row=quad*4+reg = 4 consecutive FEATURES.
__global__ __launch_bounds__(256) void gemm_dual_mfma(
    const short* __restrict__ Ab, const short* __restrict__ Wt0,
    const float* __restrict__ b0, const short* __restrict__ Wt1,
    short* __restrict__ yb, int nrows) {
  __shared__ short T1s[4][16 * TP];   // per-wave T1 tile (16 rows x 128 bf16), 17.4 KB
  int t = threadIdx.x;
  int w = t >> 6, lane = t & 63;
  int m16 = lane & 15, quad = lane >> 4;
  int v0 = blockIdx.x * 64;
  int row = v0 + w * 16 + m16;
  bool rvalid = row < nrows;
  int rc = rvalid ? row : (nrows - 1);

  // B-op fragments: this lane supplies A row `rc` (column of A^T)
  bf16x8 xfr[4];
  {
    const bf16x8* Ar = (const bf16x8*)(Ab + (size_t)rc * HID);
#pragma unroll
    for (int kc = 0; kc < 4; ++kc) xfr[kc] = Ar[kc * 4 + quad];
  }
  f32x4 acc[8];
#pragma unroll
  for (int nt = 0; nt < 8; ++nt) {
    acc[nt][0] = 0.f; acc[nt][1] = 0.f; acc[nt][2] = 0.f; acc[nt][3] = 0.f;
  }
  // GEMM1: T1^T = W0^T x A^T
#pragma unroll
  for (int nt = 0; nt < 8; ++nt) {
    const bf16x8* Wr = (const bf16x8*)(Wt0 + (size_t)(nt * 16 + m16) * HID);
#pragma unroll
    for (int kc = 0; kc < 4; ++kc)
      acc[nt] = __builtin_amdgcn_mfma_f32_16x16x32_bf16(Wr[kc * 4 + quad], xfr[kc],
                                                        acc[nt], 0, 0, 0);
  }
  // epilogue 1: relu(+b0) -> per-wave LDS tile (bf16), lane holds 4 consecutive features
  short* T1w = &T1s[w][0];
#pragma unroll
  for (int nt = 0; nt < 8; ++nt) {
    int nb = nt * 16 + quad * 4;
    float4 bv = *(const float4*)&b0[nb];
    float r0 = fmaxf(acc[nt][0] + bv.x, 0.f);
    float r1 = fmaxf(acc[nt][1] + bv.y, 0.f);
    float r2 = fmaxf(acc[nt][2] + bv.z, 0.f);
    float r3 = fmaxf(acc[nt][3] + bv.w, 0.f);
    uint2 pk;
    pk.x = pack2bf(r0, r1);
    pk.y = pack2bf(r2, r3);
    *(uint2*)&T1w[m16 * TP + nb] = pk;
    acc[nt][0] = 0.f; acc[nt][1] = 0.f; acc[nt][2] = 0.f; acc[nt][3] = 0.f;
  }
  __syncthreads();
  // reload as B-op fragments: lane supplies T1 row m16
  bf16x8 tfr[4];
#pragma unroll
  for (int kc = 0; kc < 4; ++kc)
    tfr[kc] = *(const bf16x8*)&T1w[m16 * TP + kc * 32 + quad * 8];
  // GEMM2: Y^T = W1^T x T1^T
#pragma unroll
  for (int nt = 0; nt < 8; ++nt) {
    const bf16x8* Wr = (const bf16x8*)(Wt1 + (size_t)(nt * 16 + m16) * HID);
#pragma unroll
    for (int kc = 0; kc < 4; ++kc)
      acc[nt] = __builtin_amdgcn_mfma_f32_16x16x32_bf16(Wr[kc * 4 + quad], tfr[kc],
                                                        acc[nt], 0, 0, 0);
  }
  if (rvalid) {
#pragma unroll
    for (int nt = 0; nt < 8; ++nt) {
      int nb = nt * 16 + quad * 4;
      uint2 pk;
      pk.x = pack2bf(acc[nt][0], acc[nt][1]);
      pk.y = pack2bf(acc[nt][2], acc[nt][3]);
      *(uint2*)(yb + (size_t)row * HID + nb) = pk;
    }
  }
}

// edge output: bf16 y gathers (256B/row), f32 math
__global__ __launch_bounds__(256) void edge_out_kernel(
    const int* __restrict__ csr_src, const int* __restrict__ csr_eid,
    const int* __restrict__ row_ofs, const uint4* __restrict__ yb,
    const float* __restrict__ b1, const float* __restrict__ w2,
    const float* __restrict__ b2, float* __restrict__ out) {
  int v = (blockIdx.x * blockDim.x + threadIdx.x) >> 6;
  int lane = threadIdx.x & 63;
  if (v >= N_NODES) return;
  int beg = row_ofs[v], end = row_ofs[v + 1];
  if (beg >= end) return;
  int g = lane >> 4, l = lane & 15;
  uint4 D = yb[(size_t)v * 16 + l];
  float d[8] = {BFLO(D.x), BFHI(D.x), BFLO(D.y), BFHI(D.y),
                BFLO(D.z), BFHI(D.z), BFLO(D.w), BFHI(D.w)};
  {
    float4 q0 = ((const float4*)b1)[l * 2], q1 = ((const float4*)b1)[l * 2 + 1];
    d[0] += q0.x; d[1] += q0.y; d[2] += q0.z; d[3] += q0.w;
    d[4] += q1.x; d[5] += q1.y; d[6] += q1.z; d[7] += q1.w;
  }
  float w[8];
  {
    float4 q0 = ((const float4*)w2)[l * 2], q1 = ((const float4*)w2)[l * 2 + 1];
    w[0] = q0.x; w[1] = q0.y; w[2] = q0.z; w[3] = q0.w;
    w[4] = q1.x; w[5] = q1.y; w[6] = q1.z; w[7] = q1.w;
  }
  float ob2 = b2[0];
  for (int i = beg; i < end; i += 16) {
    int ii[4]; bool qq[4]; int ss[4];
#pragma unroll
    for (int u = 0; u < 4; ++u) {
      ii[u] = i + 4 * u + g;
      qq[u] = ii[u] < end;
      ss[u] = csr_src[qq[u] ? ii[u] : beg];
    }
    uint4 A[4];
#pragma unroll
    for (int u = 0; u < 4; ++u) A[u] = yb[(size_t)ss[u] * 16 + l];
#pragma unroll
    for (int u = 0; u < 4; ++u) {
      float p = fmaxf(BFLO(A[u].x) + d[0], 0.f) * w[0] +
                fmaxf(BFHI(A[u].x) + d[1], 0.f) * w[1] +
                fmaxf(BFLO(A[u].y) + d[2], 0.f) * w[2] +
                fmaxf(BFHI(A[u].y) + d[3], 0.f) * w[3] +
                fmaxf(BFLO(A[u].z) + d[4], 0.f) * w[4] +
                fmaxf(BFHI(A[u].z) + d[5], 0.f) * w[5] +
                fmaxf(BFLO(A[u].w) + d[6], 0.f) * w[6] +
                fmaxf(BFHI(A[u].w) + d[7], 0.f) * w[7];
      p += __shfl_down(p, 8, 16);
      p += __shfl_down(p, 4, 16);
      p += __shfl_down(p, 2, 16);
      p += __shfl_down(p, 1, 16);
      if (l == 0 && qq[u]) out[csr_eid[ii[u]]] = p + ob2;
    }
  }
}

extern "C" void kernel_launch(void* const* d_in, const int* in_sizes, int n_in,
                              void* d_out, int out_size, void* d_ws, size_t ws_size,
                              hipStream_t stream) {
  const float* node_feats = (const float*)d_in[1];
  const int*   src        = (const int*)d_in[2];
  const int*   dst        = (const int*)d_in[3];
  const float* W_nemb     = (const float*)d_in[6];
  const float* b_nemb     = (const float*)d_in[7];
  const float* gnn_W      = (const float*)d_in[8];
  const float* gnn_b      = (const float*)d_in[9];
  const float* out_W1     = (const float*)d_in[10];
  const float* out_b1     = (const float*)d_in[11];
  const float* out_W2     = (const float*)d_in[12];
  const float* out_b2     = (const float*)d_in[13];
  float* out = (float*)d_out;

  size_t off = 0;
  char* base = (char*)d_ws;
  auto alloc = [&](size_t nbytes) -> char* {
    off = (off + 255) & ~(size_t)255;
    char* p = base + off;
    off += nbytes;
    return p;
  };
  int*    bcnt2    = (int*)alloc(2 * NB * 4);
  int*    bofs_d   = (int*)alloc((NB + 1) * 4);
  int*    bofs_s   = (int*)alloc((NB + 1) * 4);
  int*    cur_d    = (int*)alloc(NB * 4);
  int*    cur_s    = (int*)alloc(NB * 4);
  float*  norm_out = (float*)alloc(N_NODES * 4);
  float*  norm_in  = (float*)alloc(N_NODES * 4);
  int*    row_ofs  = (int*)alloc((N_NODES + 1) * 4);
  int*    csr_src  = (int*)alloc((size_t)N_EDGES * 4);
  int*    csr_eid  = (int*)alloc((size_t)N_EDGES * 4);
  float4* agg4     = (float4*)alloc((size_t)N_NODES * 16);
  float*  sno      = (float*)alloc(N_NODES * 4);
  short*  Wt0      = (short*)alloc((size_t)HID * HID * 2);      // bf16 W_l2^T
  short*  Wt1      = (short*)alloc((size_t)HID * HID * 2);      // bf16 out_W1^T
  uint4*  h1b      = (uint4*)alloc((size_t)N_NODES * HID * 2);  // bf16 h1*no
  short*  Ab       = (short*)alloc((size_t)N_NODES * HID * 2);  // bf16 aggregate
  short*  ybs      = (short*)alloc((size_t)N_NODES * HID * 2);  // bf16 y
  int2*   sdst     = (int2*)Ab;    // staging alias, consumed by p4 before Ab written
  int*    ssrc     = (int*)ybs;    // staging alias, consumed by p5 before yb written
  int*    bcnt_d   = bcnt2;
  int*    bcnt_s   = bcnt2 + NB;
  (void)ws_size; (void)n_in; (void)in_sizes; (void)out_size;

  hipMemsetAsync(bcnt2, 0, 2 * NB * 4, stream);
  prep_w_kernel<<<(HID * HID + 255) / 256, 256, 0, stream>>>(
      gnn_W + (size_t)HID * HID, out_W1, Wt0, Wt1);
  p1_hist_kernel<<<128, 256, 0, stream>>>(src, dst, bcnt_d, bcnt_s);
  p2_scan_kernel<<<1, 256, 0, stream>>>(bcnt_d, bcnt_s, bofs_d, bofs_s, cur_d, cur_s);
  p3_scatter_dst_kernel<<<(N_EDGES + 2047) / 2048, 256, 0, stream>>>(src, dst, cur_d, sdst);
  p3_scatter_src_kernel<<<(N_EDGES + 2047) / 2048, 256, 0, stream>>>(src, cur_s, ssrc);
  p4_csr_kernel<<<NB, 256, 0, stream>>>(sdst, bofs_d, row_ofs, norm_in, csr_src, csr_eid);
  p5_degout_kernel<<<NB, 256, 0, stream>>>(ssrc, bofs_s, norm_out);

  agg4_kernel<<<(N_NODES * 16 + 255) / 256, 256, 0, stream>>>(
      (const float4*)node_feats, norm_out, csr_src, row_ofs, agg4, sno);
  gemm_l1_kernel<<<(N_NODES + 63) / 64, 256, 0, stream>>>(
      agg4, sno, norm_in, norm_out, W_nemb, b_nemb, gnn_W, gnn_b, h1b, N_NODES);

  aggregate_kernel<<<(N_NODES * 64 + 255) / 256, 256, 0, stream>>>(
      h1b, row_ofs, csr_src, norm_in, (uint4*)Ab);

  gemm_dual_mfma<<<(N_NODES + 63) / 64, 256, 0, stream>>>(
      Ab, Wt0, gnn_b + HID, Wt1, ybs, N_NODES);

  edge_out_kernel<<<(N_NODES * 64 + 255) / 256, 256, 0, stream>>>(
      csr_src, csr_eid, row_ofs, (const uint4*)ybs, out_b1, out_W2, out_b2, out);
}

// Round 11
// 312.668 us; speedup vs baseline: 1.1561x; 1.0245x over previous
//
#include <hip/hip_runtime.h>

#define N_NODES 50000
#define N_EDGES 800000
#define HID 128
#define NB 256   // node buckets
#define NPB 196  // nodes per bucket
#define TP 136   // T1 LDS row stride in shorts

typedef __attribute__((ext_vector_type(8))) short bf16x8;
typedef __attribute__((ext_vector_type(4))) float f32x4;

__device__ __forceinline__ unsigned pack2bf(float a, float b) {
  unsigned ua = __float_as_uint(a);
  ua += 0x7FFFu + ((ua >> 16) & 1u);
  unsigned ub = __float_as_uint(b);
  ub += 0x7FFFu + ((ub >> 16) & 1u);
  return (ua >> 16) | (ub & 0xFFFF0000u);
}
#define BFLO(u) __uint_as_float((u) << 16)
#define BFHI(u) __uint_as_float((u) & 0xFFFF0000u)

__device__ __forceinline__ float2 unpk(unsigned u) {
  return make_float2(BFLO(u), BFHI(u));
}
__device__ __forceinline__ float2 f2add(float2 a, float2 b) {
  return make_float2(a.x + b.x, a.y + b.y);
}
__device__ __forceinline__ float2 f2max0(float2 a) {
  return make_float2(fmaxf(a.x, 0.f), fmaxf(a.y, 0.f));
}
__device__ __forceinline__ float2 f2fma(float2 a, float2 b, float2 c) {
  return make_float2(fmaf(a.x, b.x, c.x), fmaf(a.y, b.y, c.y));
}

// ================= bucketed CSR build =================

__global__ __launch_bounds__(256) void p1_hist_kernel(
    const int* __restrict__ src, const int* __restrict__ dst,
    int* __restrict__ bcnt_d, int* __restrict__ bcnt_s) {
  __shared__ int hd[NB], hs[NB];
  int t = threadIdx.x;
  hd[t] = 0; hs[t] = 0;
  __syncthreads();
  for (int e = blockIdx.x * 256 + t; e < N_EDGES; e += gridDim.x * 256) {
    atomicAdd(&hd[dst[e] / NPB], 1);
    atomicAdd(&hs[src[e] / NPB], 1);
  }
  __syncthreads();
  if (hd[t]) atomicAdd(&bcnt_d[t], hd[t]);
  if (hs[t]) atomicAdd(&bcnt_s[t], hs[t]);
}

__global__ void p2_scan_kernel(const int* __restrict__ bcnt_d, const int* __restrict__ bcnt_s,
                               int* __restrict__ bofs_d, int* __restrict__ bofs_s,
                               int* __restrict__ cur_d, int* __restrict__ cur_s) {
  __shared__ int s[NB];
  int t = threadIdx.x;
  int v = bcnt_d[t];
  s[t] = v;
  __syncthreads();
  for (int o = 1; o < NB; o <<= 1) {
    int x = (t >= o) ? s[t - o] : 0;
    __syncthreads();
    s[t] += x;
    __syncthreads();
  }
  int ofs = s[t] - v;
  bofs_d[t] = ofs; cur_d[t] = ofs;
  if (t == NB - 1) bofs_d[NB] = s[t];
  __syncthreads();
  v = bcnt_s[t];
  s[t] = v;
  __syncthreads();
  for (int o = 1; o < NB; o <<= 1) {
    int x = (t >= o) ? s[t - o] : 0;
    __syncthreads();
    s[t] += x;
    __syncthreads();
  }
  ofs = s[t] - v;
  bofs_s[t] = ofs; cur_s[t] = ofs;
  if (t == NB - 1) bofs_s[NB] = s[t];
}

// fused dst+src scatter: one pass over edges, two LDS histograms
__global__ __launch_bounds__(256) void p3_scatter_both_kernel(
    const int* __restrict__ src, const int* __restrict__ dst,
    int* __restrict__ cur_d, int* __restrict__ cur_s,
    int2* __restrict__ sdst, int* __restrict__ ssrc) {
  __shared__ int bcd[NB], bbd[NB], bcs[NB], bbs[NB];
  int t = threadIdx.x;
  int base = blockIdx.x * 2048;
  bcd[t] = 0; bcs[t] = 0;
  __syncthreads();
  int mybd[8], myrd[8], mys[8], myp[8], mybs[8], myrs[8];
#pragma unroll
  for (int u = 0; u < 8; ++u) {
    int e = base + u * 256 + t;
    mybd[u] = -1;
    if (e < N_EDGES) {
      int s = src[e], d = dst[e];
      int bd = d / NPB;
      mybd[u] = bd;
      myrd[u] = atomicAdd(&bcd[bd], 1);
      mys[u] = s;
      myp[u] = ((d - bd * NPB) << 20) | e;
      int bs = s / NPB;
      mybs[u] = bs;
      myrs[u] = atomicAdd(&bcs[bs], 1);
    }
  }
  __syncthreads();
  {
    int cd = bcd[t];
    if (cd) bbd[t] = atomicAdd(&cur_d[t], cd);
    int cs = bcs[t];
    if (cs) bbs[t] = atomicAdd(&cur_s[t], cs);
  }
  __syncthreads();
#pragma unroll
  for (int u = 0; u < 8; ++u) {
    if (mybd[u] >= 0) {
      sdst[bbd[mybd[u]] + myrd[u]] = make_int2(mys[u], myp[u]);
      ssrc[bbs[mybs[u]] + myrs[u]] = mys[u];
    }
  }
}

__global__ __launch_bounds__(256) void p4_csr_kernel(
    const int2* __restrict__ sdst, const int* __restrict__ bofs_d,
    int* __restrict__ row_ofs, float* __restrict__ norm_in,
    int* __restrict__ csr_src, int* __restrict__ csr_eid) {
  __shared__ int hc[NB], sc[NB], cur[NB];
  int b = blockIdx.x, t = threadIdx.x;
  int base = bofs_d[b], cnt = bofs_d[b + 1] - base;
  hc[t] = 0;
  __syncthreads();
  for (int i = t; i < cnt; i += 256) atomicAdd(&hc[sdst[base + i].y >> 20], 1);
  __syncthreads();
  int v = hc[t];
  sc[t] = v;
  __syncthreads();
  for (int o = 1; o < NB; o <<= 1) {
    int x = (t >= o) ? sc[t - o] : 0;
    __syncthreads();
    sc[t] += x;
    __syncthreads();
  }
  int ofs = sc[t] - v;
  int node = b * NPB + t;
  if (t < NPB && node < N_NODES) {
    row_ofs[node] = base + ofs;
    norm_in[node] = rsqrtf((float)(v < 1 ? 1 : v));
  }
  cur[t] = base + ofs;
  if (b == 0 && t == 0) row_ofs[N_NODES] = N_EDGES;
  __syncthreads();
  for (int i = t; i < cnt; i += 256) {
    int2 e = sdst[base + i];
    int pos = atomicAdd(&cur[e.y >> 20], 1);
    csr_src[pos] = e.x;
    csr_eid[pos] = e.y & 0xFFFFF;
  }
}

__global__ __launch_bounds__(256) void p5_degout_kernel(
    const int* __restrict__ ssrc, const int* __restrict__ bofs_s,
    float* __restrict__ norm_out) {
  __shared__ int hc[NB];
  int b = blockIdx.x, t = threadIdx.x;
  int base = bofs_s[b], cnt = bofs_s[b + 1] - base;
  int lo = b * NPB;
  hc[t] = 0;
  __syncthreads();
  for (int i = t; i < cnt; i += 256) atomicAdd(&hc[ssrc[base + i] - lo], 1);
  __syncthreads();
  int node = lo + t;
  if (t < NPB && node < N_NODES) {
    int v = hc[t];
    norm_out[node] = rsqrtf((float)(v < 1 ? 1 : v));
  }
}

// W prep: bf16 transposes of layer-1 W, layer-2 W, out_W1
__global__ __launch_bounds__(256) void prep_w_kernel(
    const float* __restrict__ Wa, const float* __restrict__ Wb,
    const float* __restrict__ Wc, short* __restrict__ Wta,
    short* __restrict__ Wtb, short* __restrict__ Wtc) {
  int t = blockIdx.x * 256 + threadIdx.x;
  if (t < HID * HID) {
    int k = t >> 7, n = t & 127;
    Wta[n * HID + k] = (short)(pack2bf(Wa[t], 0.f) & 0xFFFFu);
    Wtb[n * HID + k] = (short)(pack2bf(Wb[t], 0.f) & 0xFFFFu);
    Wtc[n * HID + k] = (short)(pack2bf(Wc[t], 0.f) & 0xFFFFu);
  }
}

// ================= model kernels =================

__global__ __launch_bounds__(256) void agg4_kernel(
    const float4* __restrict__ nf4, const float* __restrict__ no_,
    const int* __restrict__ csr_src, const int* __restrict__ row_ofs,
    float4* __restrict__ agg4, float* __restrict__ sno) {
  int wid = (blockIdx.x * blockDim.x + threadIdx.x) >> 6;
  int lane = threadIdx.x & 63;
  int g = lane >> 4, l = lane & 15;
  int v = wid * 4 + g;
  if (v >= N_NODES) return;
  int beg = row_ofs[v], end = row_ofs[v + 1];
  float ax = 0.f, ay = 0.f, az = 0.f, aw = 0.f, sn = 0.f;
  for (int i = beg + l; i < end; i += 16) {
    int s = csr_src[i];
    float w = no_[s];
    float4 n = nf4[s];
    ax += n.x * w; ay += n.y * w; az += n.z * w; aw += n.w * w;
    sn += w;
  }
#pragma unroll
  for (int o = 1; o < 16; o <<= 1) {
    ax += __shfl_xor(ax, o, 16);
    ay += __shfl_xor(ay, o, 16);
    az += __shfl_xor(az, o, 16);
    aw += __shfl_xor(aw, o, 16);
    sn += __shfl_xor(sn, o, 16);
  }
  if (l == 0) {
    agg4[v] = make_float4(ax, ay, az, aw);
    sno[v] = sn;
  }
}

// layer-1 fully fused via MFMA: expand 4->128 per-lane in B-frag layout, no LDS.
// h1^T = W0^T (A-op) x X^T (B-op); C/D col=node, row=feature.
__global__ __launch_bounds__(256) void gemm_l1_mfma(
    const float4* __restrict__ agg4, const float* __restrict__ sno,
    const float* __restrict__ ni_, const float* __restrict__ no_,
    const float* __restrict__ Wn, const float* __restrict__ bn,
    const short* __restrict__ Wt0, const float* __restrict__ b0,
    short* __restrict__ h1b, int nrows) {
  int t = threadIdx.x;
  int w = t >> 6, lane = t & 63;
  int m16 = lane & 15, quad = lane >> 4;
  int v0 = blockIdx.x * 64;
  int row = v0 + w * 16 + m16;
  bool rvalid = row < nrows;
  int rc = rvalid ? row : (nrows - 1);
  float4 a = agg4[rc];
  float sn = sno[rc], nin = ni_[rc];

  // compute this lane's 32 expanded features, pack to bf16 B-fragments
  bf16x8 xfr[4];
#pragma unroll
  for (int kc = 0; kc < 4; ++kc) {
    union { unsigned u[4]; bf16x8 v; } cv;
#pragma unroll
    for (int jj = 0; jj < 4; ++jj) {
      int k0 = kc * 32 + quad * 8 + jj * 2;
      float x0 = (a.x * Wn[k0] + a.y * Wn[HID + k0] + a.z * Wn[2 * HID + k0] +
                  a.w * Wn[3 * HID + k0] + bn[k0] * sn) * nin;
      int k1 = k0 + 1;
      float x1 = (a.x * Wn[k1] + a.y * Wn[HID + k1] + a.z * Wn[2 * HID + k1] +
                  a.w * Wn[3 * HID + k1] + bn[k1] * sn) * nin;
      cv.u[jj] = pack2bf(x0, x1);
    }
    xfr[kc] = cv.v;
  }
  f32x4 acc[8];
#pragma unroll
  for (int nt = 0; nt < 8; ++nt) {
    acc[nt][0] = 0.f; acc[nt][1] = 0.f; acc[nt][2] = 0.f; acc[nt][3] = 0.f;
  }
#pragma unroll
  for (int nt = 0; nt < 8; ++nt) {
    const bf16x8* Wr = (const bf16x8*)(Wt0 + (size_t)(nt * 16 + m16) * HID);
#pragma unroll
    for (int kc = 0; kc < 4; ++kc)
      acc[nt] = __builtin_amdgcn_mfma_f32_16x16x32_bf16(Wr[kc * 4 + quad], xfr[kc],
                                                        acc[nt], 0, 0, 0);
  }
  if (rvalid) {
    float nov = no_[row];
#pragma unroll
    for (int nt = 0; nt < 8; ++nt) {
      int nb = nt * 16 + quad * 4;
      float4 bv = *(const float4*)&b0[nb];
      float r0 = fmaxf(acc[nt][0] + bv.x, 0.f) * nov;
      float r1 = fmaxf(acc[nt][1] + bv.y, 0.f) * nov;
      float r2 = fmaxf(acc[nt][2] + bv.z, 0.f) * nov;
      float r3 = fmaxf(acc[nt][3] + bv.w, 0.f) * nov;
      uint2 pk;
      pk.x = pack2bf(r0, r1);
      pk.y = pack2bf(r2, r3);
      *(uint2*)(h1b + (size_t)row * HID + nb) = pk;
    }
  }
}

// layer-2 aggregate: bf16 gathers, zero-row for invalid slots, float2 packed adds
__global__ __launch_bounds__(256) void aggregate_kernel(
    const uint4* __restrict__ hb, const int* __restrict__ row_ofs,
    const int* __restrict__ csr_src, const float* __restrict__ ni_,
    uint4* __restrict__ Ab) {
  int v = (blockIdx.x * blockDim.x + threadIdx.x) >> 6;
  int lane = threadIdx.x & 63;
  if (v >= N_NODES) return;
  int beg = row_ofs[v], end = row_ofs[v + 1];
  int g = lane >> 4, l = lane & 15;
  float2 acc2[4];
#pragma unroll
  for (int j = 0; j < 4; ++j) acc2[j] = make_float2(0.f, 0.f);
  for (int i = beg; i < end; i += 16) {
    int ss[4];
#pragma unroll
    for (int u = 0; u < 4; ++u) {
      int ii = i + 4 * u + g;
      ss[u] = (ii < end) ? csr_src[ii] : N_NODES;  // zero row
    }
    uint4 X[4];
#pragma unroll
    for (int u = 0; u < 4; ++u) X[u] = hb[(size_t)ss[u] * 16 + l];
#pragma unroll
    for (int u = 0; u < 4; ++u) {
      acc2[0] = f2add(acc2[0], unpk(X[u].x));
      acc2[1] = f2add(acc2[1], unpk(X[u].y));
      acc2[2] = f2add(acc2[2], unpk(X[u].z));
      acc2[3] = f2add(acc2[3], unpk(X[u].w));
    }
  }
#pragma unroll
  for (int j = 0; j < 4; ++j) {
    acc2[j].x += __shfl_xor(acc2[j].x, 16, 64);
    acc2[j].x += __shfl_xor(acc2[j].x, 32, 64);
    acc2[j].y += __shfl_xor(acc2[j].y, 16, 64);
    acc2[j].y += __shfl_xor(acc2[j].y, 32, 64);
  }
  if (g == 0) {
    float n = ni_[v];
    uint4 pk;
    pk.x = pack2bf(acc2[0].x * n, acc2[0].y * n);
    pk.y = pack2bf(acc2[1].x * n, acc2[1].y * n);
    pk.z = pack2bf(acc2[2].x * n, acc2[2].y * n);
    pk.w = pack2bf(acc2[3].x * n, acc2[3].y * n);
    Ab[(size_t)v * 16 + l] = pk;
  }
}

// fused layer-2 GEMM + output GEMM via MFMA (unchanged, verified R9)
__global__ __launch_bounds__(256) void gemm_dual_mfma(
    const short* __restrict__ Ab, const short* __restrict__ Wt0,
    const float* __restrict__ b0, const short* __restrict__ Wt1,
    short* __restrict__ yb, int nrows) {
  __shared__ short T1s[4][16 * TP];
  int t = threadIdx.x;
  int w = t >> 6, lane = t & 63;
  int m16 = lane & 15, quad = lane >> 4;
  int v0 = blockIdx.x * 64;
  int row = v0 + w * 16 + m16;
  bool rvalid = row < nrows;
  int rc = rvalid ? row : (nrows - 1);

  bf16x8 xfr[4];
  {
    const bf16x8* Ar = (const bf16x8*)(Ab + (size_t)rc * HID);
#pragma unroll
    for (int kc = 0; kc < 4; ++kc) xfr[kc] = Ar[kc * 4 + quad];
  }
  f32x4 acc[8];
#pragma unroll
  for (int nt = 0; nt < 8; ++nt) {
    acc[nt][0] = 0.f; acc[nt][1] = 0.f; acc[nt][2] = 0.f; acc[nt][3] = 0.f;
  }
#pragma unroll
  for (int nt = 0; nt < 8; ++nt) {
    const bf16x8* Wr = (const bf16x8*)(Wt0 + (size_t)(nt * 16 + m16) * HID);
#pragma unroll
    for (int kc = 0; kc < 4; ++kc)
      acc[nt] = __builtin_amdgcn_mfma_f32_16x16x32_bf16(Wr[kc * 4 + quad], xfr[kc],
                                                        acc[nt], 0, 0, 0);
  }
  short* T1w = &T1s[w][0];
#pragma unroll
  for (int nt = 0; nt < 8; ++nt) {
    int nb = nt * 16 + quad * 4;
    float4 bv = *(const float4*)&b0[nb];
    float r0 = fmaxf(acc[nt][0] + bv.x, 0.f);
    float r1 = fmaxf(acc[nt][1] + bv.y, 0.f);
    float r2 = fmaxf(acc[nt][2] + bv.z, 0.f);
    float r3 = fmaxf(acc[nt][3] + bv.w, 0.f);
    uint2 pk;
    pk.x = pack2bf(r0, r1);
    pk.y = pack2bf(r2, r3);
    *(uint2*)&T1w[m16 * TP + nb] = pk;
    acc[nt][0] = 0.f; acc[nt][1] = 0.f; acc[nt][2] = 0.f; acc[nt][3] = 0.f;
  }
  __syncthreads();
  bf16x8 tfr[4];
#pragma unroll
  for (int kc = 0; kc < 4; ++kc)
    tfr[kc] = *(const bf16x8*)&T1w[m16 * TP + kc * 32 + quad * 8];
#pragma unroll
  for (int nt = 0; nt < 8; ++nt) {
    const bf16x8* Wr = (const bf16x8*)(Wt1 + (size_t)(nt * 16 + m16) * HID);
#pragma unroll
    for (int kc = 0; kc < 4; ++kc)
      acc[nt] = __builtin_amdgcn_mfma_f32_16x16x32_bf16(Wr[kc * 4 + quad], tfr[kc],
                                                        acc[nt], 0, 0, 0);
  }
  if (rvalid) {
#pragma unroll
    for (int nt = 0; nt < 8; ++nt) {
      int nb = nt * 16 + quad * 4;
      uint2 pk;
      pk.x = pack2bf(acc[nt][0], acc[nt][1]);
      pk.y = pack2bf(acc[nt][2], acc[nt][3]);
      *(uint2*)(yb + (size_t)row * HID + nb) = pk;
    }
  }
}

// edge output: bf16 y gathers, float2 packed math
__global__ __launch_bounds__(256) void edge_out_kernel(
    const int* __restrict__ csr_src, const int* __restrict__ csr_eid,
    const int* __restrict__ row_ofs, const uint4* __restrict__ yb,
    const float* __restrict__ b1, const float* __restrict__ w2,
    const float* __restrict__ b2, float* __restrict__ out) {
  int v = (blockIdx.x * blockDim.x + threadIdx.x) >> 6;
  int lane = threadIdx.x & 63;
  if (v >= N_NODES) return;
  int beg = row_ofs[v], end = row_ofs[v + 1];
  if (beg >= end) return;
  int g = lane >> 4, l = lane & 15;
  const float2* b12 = (const float2*)b1;
  const float2* w22 = (const float2*)w2;
  uint4 D = yb[(size_t)v * 16 + l];
  float2 d0 = f2add(unpk(D.x), b12[l * 4 + 0]);
  float2 d1 = f2add(unpk(D.y), b12[l * 4 + 1]);
  float2 d2 = f2add(unpk(D.z), b12[l * 4 + 2]);
  float2 d3 = f2add(unpk(D.w), b12[l * 4 + 3]);
  float2 w0 = w22[l * 4 + 0], w1 = w22[l * 4 + 1];
  float2 w2v = w22[l * 4 + 2], w3 = w22[l * 4 + 3];
  float ob2 = b2[0];
  for (int i = beg; i < end; i += 16) {
    int ii[4]; bool qq[4]; int ss[4];
#pragma unroll
    for (int u = 0; u < 4; ++u) {
      ii[u] = i + 4 * u + g;
      qq[u] = ii[u] < end;
      ss[u] = csr_src[qq[u] ? ii[u] : beg];
    }
    uint4 A[4];
#pragma unroll
    for (int u = 0; u < 4; ++u) A[u] = yb[(size_t)ss[u] * 16 + l];
#pragma unroll
    for (int u = 0; u < 4; ++u) {
      float2 p2;
      p2.x = 0.f; p2.y = 0.f;
      p2 = f2fma(f2max0(f2add(unpk(A[u].x), d0)), w0, p2);
      p2 = f2fma(f2max0(f2add(unpk(A[u].y), d1)), w1, p2);
      p2 = f2fma(f2max0(f2add(unpk(A[u].z), d2)), w2v, p2);
      p2 = f2fma(f2max0(f2add(unpk(A[u].w), d3)), w3, p2);
      float p = p2.x + p2.y;
      p += __shfl_down(p, 8, 16);
      p += __shfl_down(p, 4, 16);
      p += __shfl_down(p, 2, 16);
      p += __shfl_down(p, 1, 16);
      if (l == 0 && qq[u]) out[csr_eid[ii[u]]] = p + ob2;
    }
  }
}

extern "C" void kernel_launch(void* const* d_in, const int* in_sizes, int n_in,
                              void* d_out, int out_size, void* d_ws, size_t ws_size,
                              hipStream_t stream) {
  const float* node_feats = (const float*)d_in[1];
  const int*   src        = (const int*)d_in[2];
  const int*   dst        = (const int*)d_in[3];
  const float* W_nemb     = (const float*)d_in[6];
  const float* b_nemb     = (const float*)d_in[7];
  const float* gnn_W      = (const float*)d_in[8];
  const float* gnn_b      = (const float*)d_in[9];
  const float* out_W1     = (const float*)d_in[10];
  const float* out_b1     = (const float*)d_in[11];
  const float* out_W2     = (const float*)d_in[12];
  const float* out_b2     = (const float*)d_in[13];
  float* out = (float*)d_out;

  size_t off = 0;
  char* base = (char*)d_ws;
  auto alloc = [&](size_t nbytes) -> char* {
    off = (off + 255) & ~(size_t)255;
    char* p = base + off;
    off += nbytes;
    return p;
  };
  int*    bcnt2    = (int*)alloc(2 * NB * 4);
  int*    bofs_d   = (int*)alloc((NB + 1) * 4);
  int*    bofs_s   = (int*)alloc((NB + 1) * 4);
  int*    cur_d    = (int*)alloc(NB * 4);
  int*    cur_s    = (int*)alloc(NB * 4);
  float*  norm_out = (float*)alloc(N_NODES * 4);
  float*  norm_in  = (float*)alloc(N_NODES * 4);
  int*    row_ofs  = (int*)alloc((N_NODES + 1) * 4);
  int*    csr_src  = (int*)alloc((size_t)N_EDGES * 4);
  int*    csr_eid  = (int*)alloc((size_t)N_EDGES * 4);
  float4* agg4     = (float4*)alloc((size_t)N_NODES * 16);
  float*  sno      = (float*)alloc(N_NODES * 4);
  short*  Wta      = (short*)alloc((size_t)HID * HID * 2);  // bf16 W_l1^T
  short*  Wtb      = (short*)alloc((size_t)HID * HID * 2);  // bf16 W_l2^T
  short*  Wtc     = (short*)alloc((size_t)HID * HID * 2);   // bf16 out_W1^T
  short*  h1b      = (short*)alloc((size_t)(N_NODES + 1) * HID * 2);  // +zero row
  short*  Ab       = (short*)alloc((size_t)N_NODES * HID * 2);
  short*  ybs      = (short*)alloc((size_t)N_NODES * HID * 2);
  int2*   sdst     = (int2*)Ab;    // staging alias, consumed by p4 before Ab written
  int*    ssrc     = (int*)ybs;    // staging alias, consumed by p5 before yb written
  int*    bcnt_d   = bcnt2;
  int*    bcnt_s   = bcnt2 + NB;
  (void)ws_size; (void)n_in; (void)in_sizes; (void)out_size;

  hipMemsetAsync(bcnt2, 0, 2 * NB * 4, stream);
  hipMemsetAsync(h1b + (size_t)N_NODES * HID, 0, HID * 2, stream);  // zero row
  prep_w_kernel<<<(HID * HID + 255) / 256, 256, 0, stream>>>(
      gnn_W, gnn_W + (size_t)HID * HID, out_W1, Wta, Wtb, Wtc);
  p1_hist_kernel<<<128, 256, 0, stream>>>(src, dst, bcnt_d, bcnt_s);
  p2_scan_kernel<<<1, 256, 0, stream>>>(bcnt_d, bcnt_s, bofs_d, bofs_s, cur_d, cur_s);
  p3_scatter_both_kernel<<<(N_EDGES + 2047) / 2048, 256, 0, stream>>>(
      src, dst, cur_d, cur_s, sdst, ssrc);
  p4_csr_kernel<<<NB, 256, 0, stream>>>(sdst, bofs_d, row_ofs, norm_in, csr_src, csr_eid);
  p5_degout_kernel<<<NB, 256, 0, stream>>>(ssrc, bofs_s, norm_out);

  agg4_kernel<<<(N_NODES * 16 + 255) / 256, 256, 0, stream>>>(
      (const float4*)node_feats, norm_out, csr_src, row_ofs, agg4, sno);
  gemm_l1_mfma<<<(N_NODES + 63) / 64, 256, 0, stream>>>(
      agg4, sno, norm_in, norm_out, W_nemb, b_nemb, Wta, gnn_b, h1b, N_NODES);

  aggregate_kernel<<<(N_NODES * 64 + 255) / 256, 256, 0, stream>>>(
      (const uint4*)h1b, row_ofs, csr_src, norm_in, (uint4*)Ab);

  gemm_dual_mfma<<<(N_NODES + 63) / 64, 256, 0, stream>>>(
      Ab, Wtb, gnn_b + HID, Wtc, ybs, N_NODES);

  edge_out_kernel<<<(N_NODES * 64 + 255) / 256, 256, 0, stream>>>(
      csr_src, csr_eid, row_ofs, (const uint4*)ybs, out_b1, out_W2, out_b2, out);
}